// Round 11
// baseline (1045.972 us; speedup 1.0000x reference)
//
#include <hip/hip_runtime.h>
#include <hip/hip_bf16.h>

#define NUM_EMB 1024
#define EMB_DIM 64
#define NPIX    131072                 // 32*64*64 pixels
#define ZQ_ELEMS 8388608               // NPIX * EMB_DIM
#define ZSTRIDE 65                     // padded f32 LDS stride (conflict-free)
#define NACC    64                     // spread loss accumulators
#define RLIST   16

// d_out FLOAT32: [ z_q (8388608, b-c-h-w) | loss (1) | enc (131072) ]
// d_ws: [ E'frag 128KB | e2 f32 4KB | lossAcc f32[64] @135168 ]

typedef __attribute__((ext_vector_type(8))) short short8_t;  // bf16x8 frag
typedef __attribute__((ext_vector_type(4))) float f32x4;     // mfma acc

__global__ void vq_zero_ws(float* __restrict__ loss_out, float* __restrict__ wsAcc) {
    if (threadIdx.x == 0) loss_out[0] = 0.f;
    wsAcc[threadIdx.x] = 0.f;          // 64 threads
}

// numpy pairwise-sum (n=64, 8-accumulator) of x[j]^2 — token-identical to the
// round-5..10 PASSING kernels (bit-matches np.sum(x**2, axis=-1)).
__device__ __forceinline__ float np_sumsq64(const float* __restrict__ x) {
    float q[EMB_DIM];
    #pragma unroll
    for (int c = 0; c < EMB_DIM; ++c) q[c] = x[c] * x[c];
    float r0 = q[0], r1 = q[1], r2 = q[2], r3 = q[3];
    float r4 = q[4], r5 = q[5], r6 = q[6], r7 = q[7];
    #pragma unroll
    for (int g = 1; g < 8; ++g) {
        r0 += q[8 * g + 0]; r1 += q[8 * g + 1];
        r2 += q[8 * g + 2]; r3 += q[8 * g + 3];
        r4 += q[8 * g + 4]; r5 += q[8 * g + 5];
        r6 += q[8 * g + 6]; r7 += q[8 * g + 7];
    }
    return ((r0 + r1) + (r2 + r3)) + ((r4 + r5) + (r6 + r7));
}

__device__ __forceinline__ unsigned long long packvk(float v, int k) {
    unsigned u = __float_as_uint(v);
    u = (u & 0x80000000u) ? ~u : (u | 0x80000000u);   // monotonic f32 -> u32
    return ((unsigned long long)u << 32) | (unsigned)k;
}

// Prep: E'frag (swizzled for coalesced A-frag loads) + np-exact e2. (unchanged)
__global__ __launch_bounds__(256) void vq_prep(const float* __restrict__ emb,
                                               short* __restrict__ wsE,
                                               float* __restrict__ wsE2) {
    #pragma clang fp contract(off)
    int t    = blockIdx.x * 256 + threadIdx.x;    // grid = 16 x 256 = 4096
    int l    = t & 63;
    int ch   = (t >> 6) & 15;
    int q    = t >> 10;
    int code = q * 256 + ch * 16 + (l & 15);
    const float* ek = emb + code * EMB_DIM;
    #pragma unroll
    for (int h = 0; h < 2; ++h) {
        short8_t pk;
        #pragma unroll
        for (int j = 0; j < 8; ++j) {
            int chan = 32 * h + 8 * (l >> 4) + j;
            __hip_bfloat16 bv = __float2bfloat16(-2.0f * ek[chan]);
            unsigned short u; __builtin_memcpy(&u, &bv, 2);
            pk[j] = (short)u;
        }
        *(short8_t*)(wsE + t * 16 + h * 8) = pk;
    }
    if (t < NUM_EMB) wsE2[t] = np_sumsq64(emb + t * EMB_DIM);
}

// top-2 insert of (v,kk)
#define TOP2_INS(pg, v, kk)                                            \
    {                                                                  \
        bool lt1 = (v) < b1[pg];                                       \
        bool lt2 = (v) < b2[pg];                                       \
        b2[pg] = lt1 ? b1[pg] : (lt2 ? (v) : b2[pg]);                  \
        i2[pg] = lt1 ? i1[pg] : (lt2 ? (kk) : i2[pg]);                 \
        b1[pg] = lt1 ? (v) : b1[pg];                                   \
        i1[pg] = lt1 ? (kk) : i1[pg];                                  \
    }

// ---------------------------------------------------------------------------
// Main: 4 waves x 64 px/block; wave w screens quarter w with ONE MFMA pass,
// tracking per-pixel top-2. Resolve: thr = global-min + band; candidates =
// wave b1's <= thr; if ANY wave's b2 <= thr -> block-wide exact rescan
// (detection is complete: a missed in-band code forces its wave's b2 <= thr).
// Exact eval / rescan use the proven np-f32 token sequence.
// ---------------------------------------------------------------------------
__global__ __launch_bounds__(256, 4) void vq_mfma(const float* __restrict__ z_e,
                                                  const float* __restrict__ emb,
                                                  const short* __restrict__ wsE,
                                                  const float* __restrict__ wsE2,
                                                  float* __restrict__ zq_out,
                                                  float* __restrict__ enc_out,
                                                  float* __restrict__ wsAcc) {
    #pragma clang fp contract(off)
    __shared__ float sZf[64 * ZSTRIDE];           // 16.6 KB exact f32 z tile
    __shared__ float sE2[NUM_EMB];                // 4 KB
    __shared__ float sC1[4][64], sC2[4][64];      // wave top-2 screen scores
    __shared__ int   sI1[4][64], sI2[4][64];
    __shared__ float sBand[64], sZZ[64];
    __shared__ int   sBest[64];
    __shared__ int   sResCnt, sResList[RLIST], sResOver;
    __shared__ unsigned long long sResPack;

    const int tid  = threadIdx.x;
    const int w    = tid >> 6;
    const int lane = tid & 63;
    const int p0   = blockIdx.x * 64;
    const int b    = p0 >> 12;                    // uniform (64 | 4096)
    const int hw0  = p0 & 4095;
    const float* base = z_e + (size_t)b * (EMB_DIM * 4096) + hw0;

    *(f32x4*)&sE2[tid * 4] = *(const f32x4*)&wsE2[tid * 4];
    if (tid == 0) { sResCnt = 0; sResOver = 0; }

    // --- tile load: thread -> pixel lane, channels 16w..16w+15 (coalesced) ---
    {
        const float* zp = base + lane;
        float v[16];
        #pragma unroll
        for (int j = 0; j < 16; ++j) v[j] = zp[(size_t)(16 * w + j) * 4096];
        #pragma unroll
        for (int j = 0; j < 16; ++j) sZf[lane * ZSTRIDE + 16 * w + j] = v[j];
    }
    __syncthreads();                               // B1

    // --- wave0: np-exact zz + band (overlaps other waves' screen) ---
    if (w == 0) {
        const float* zl = &sZf[lane * ZSTRIDE];
        float rr[8] = {0,0,0,0,0,0,0,0};
        float sab = 0.f;
        #pragma unroll
        for (int g = 0; g < 8; ++g)
            #pragma unroll
            for (int j = 0; j < 8; ++j) {
                float zc = zl[8 * g + j];
                float qq = zc * zc;               // separate mul (contract off)
                rr[j] += qq;                      // g-ascending per j = np order
                sab += fabsf(zc);
            }
        sZZ[lane]   = ((rr[0] + rr[1]) + (rr[2] + rr[3])) + ((rr[4] + rr[5]) + (rr[6] + rr[7]));
        sBand[lane] = 2.0f * (9e-6f * sab + 2e-5f);
    }

    // --- B fragments from f32 LDS, pinned ---
    short8_t bfrag[4][2];
    #pragma unroll
    for (int pg = 0; pg < 4; ++pg)
        #pragma unroll
        for (int h = 0; h < 2; ++h) {
            int bpr = pg * 16 + (lane & 15);
            int c0  = 32 * h + 8 * (lane >> 4);
            short8_t pk;
            #pragma unroll
            for (int j = 0; j < 8; ++j) {
                __hip_bfloat16 bv = __float2bfloat16(sZf[bpr * ZSTRIDE + c0 + j]);
                unsigned short u; __builtin_memcpy(&u, &bv, 2);
                pk[j] = (short)u;
            }
            asm volatile("" : "+v"(pk));
            bfrag[pg][h] = pk;
        }

    const short8_t* ef = (const short8_t*)wsE + (size_t)w * 2048;

    // ===== SINGLE SCREEN PASS: top-2 per (lane, pg); 2-deep prefetch =====
    float b1[4] = {1e30f, 1e30f, 1e30f, 1e30f};
    float b2[4] = {1e30f, 1e30f, 1e30f, 1e30f};
    int   i1[4] = {0, 0, 0, 0}, i2[4] = {0, 0, 0, 0};
    {
        short8_t A0a = ef[(0 * 64 + lane) * 2 + 0];
        short8_t A1a = ef[(0 * 64 + lane) * 2 + 1];
        short8_t A0b = ef[(1 * 64 + lane) * 2 + 0];
        short8_t A1b = ef[(1 * 64 + lane) * 2 + 1];
        #pragma unroll 1
        for (int ch = 0; ch < 16; ch += 2) {
            {   // even half: uses (A0a,A1a), prefetches ch+2
                int chn = ch + 2 < 16 ? ch + 2 : 15;
                short8_t N0 = ef[(chn * 64 + lane) * 2 + 0];
                short8_t N1 = ef[(chn * 64 + lane) * 2 + 1];
                int kbase = w * 256 + ch * 16 + 4 * (lane >> 4);
                f32x4 e2v = *(const f32x4*)(&sE2[kbase]);
                #pragma unroll
                for (int pg = 0; pg < 4; ++pg) {
                    f32x4 acc = e2v;
                    acc = __builtin_amdgcn_mfma_f32_16x16x32_bf16(A0a, bfrag[pg][0], acc, 0, 0, 0);
                    acc = __builtin_amdgcn_mfma_f32_16x16x32_bf16(A1a, bfrag[pg][1], acc, 0, 0, 0);
                    #pragma unroll
                    for (int j = 0; j < 4; ++j) TOP2_INS(pg, acc[j], kbase + j);
                }
                A0a = N0; A1a = N1;
            }
            {   // odd half: uses (A0b,A1b), prefetches ch+3
                int chn = ch + 3 < 16 ? ch + 3 : 15;
                short8_t N0 = ef[(chn * 64 + lane) * 2 + 0];
                short8_t N1 = ef[(chn * 64 + lane) * 2 + 1];
                int kbase = w * 256 + (ch + 1) * 16 + 4 * (lane >> 4);
                f32x4 e2v = *(const f32x4*)(&sE2[kbase]);
                #pragma unroll
                for (int pg = 0; pg < 4; ++pg) {
                    f32x4 acc = e2v;
                    acc = __builtin_amdgcn_mfma_f32_16x16x32_bf16(A0b, bfrag[pg][0], acc, 0, 0, 0);
                    acc = __builtin_amdgcn_mfma_f32_16x16x32_bf16(A1b, bfrag[pg][1], acc, 0, 0, 0);
                    #pragma unroll
                    for (int j = 0; j < 4; ++j) TOP2_INS(pg, acc[j], kbase + j);
                }
                A0b = N0; A1b = N1;
            }
        }
    }

    // merge top-2 across lane-groups (xor 16, 32)
    #pragma unroll
    for (int step = 16; step <= 32; step <<= 1) {
        #pragma unroll
        for (int pg = 0; pg < 4; ++pg) {
            float pb1 = __shfl_xor(b1[pg], step, 64); int pi1 = __shfl_xor(i1[pg], step, 64);
            float pb2 = __shfl_xor(b2[pg], step, 64); int pi2 = __shfl_xor(i2[pg], step, 64);
            bool take = pb1 < b1[pg];
            float l1  = take ? b1[pg] : pb1;  int li1 = take ? i1[pg] : pi1;  // loser-of-firsts
            float wb2 = take ? pb2 : b2[pg];  int wi2 = take ? pi2 : i2[pg];  // winner's 2nd
            b1[pg] = take ? pb1 : b1[pg];     i1[pg] = take ? pi1 : i1[pg];
            bool s2 = wb2 < l1;
            b2[pg] = s2 ? wb2 : l1;           i2[pg] = s2 ? wi2 : li1;
        }
    }
    if (lane < 16) {
        #pragma unroll
        for (int pg = 0; pg < 4; ++pg) {
            int px = pg * 16 + lane;
            sC1[w][px] = b1[pg]; sI1[w][px] = i1[pg];
            sC2[w][px] = b2[pg]; sI2[w][px] = i2[pg];
        }
    }
    __syncthreads();                               // B2

    // ===== RESOLVE (tid<64 = pixel) =====
    if (tid < 64) {
        int px = tid;
        float m = fminf(fminf(sC1[0][px], sC1[1][px]), fminf(sC1[2][px], sC1[3][px]));
        float thr = m + sBand[px];
        bool trig = (sC2[0][px] <= thr) | (sC2[1][px] <= thr) |
                    (sC2[2][px] <= thr) | (sC2[3][px] <= thr);
        if (trig) {
            int slot = atomicAdd(&sResCnt, 1);
            if (slot < RLIST) sResList[slot] = px; else sResOver = 1;
        } else {
            int ck[4]; int nc = 0;
            #pragma unroll
            for (int w2 = 0; w2 < 4; ++w2)
                if (sC1[w2][px] <= thr) ck[nc++] = sI1[w2][px];
            if (nc == 1) {
                sBest[px] = ck[0];                 // unique in-band -> np argmin
            } else {
                const float* zl = &sZf[px * ZSTRIDE];
                float zzv = sZZ[px];
                float bestv = 1e30f; int bestk = 0x7FFFFFFF;
                for (int s = 0; s < nc; ++s) {
                    int k = ck[s];
                    const float* ek = emb + k * EMB_DIM;
                    float acc = 0.f;
                    #pragma unroll 8
                    for (int c = 0; c < EMB_DIM; ++c)   // sequential fmaf = BLAS order
                        acc = fmaf(ek[c], zl[c], acc);
                    float v = (zzv + sE2[k]) - 2.0f * acc;  // exact np tokens
                    if (v < bestv || (v == bestv && k < bestk)) { bestv = v; bestk = k; }
                }
                sBest[px] = bestk;
            }
        }
    }
    __syncthreads();                               // B3

    // ===== block-wide exact rescan for flagged pixels (rare) =====
    {
        int over = sResOver;
        int nres = over ? 64 : (sResCnt < RLIST ? sResCnt : RLIST);
        for (int r = 0; r < nres; ++r) {
            int px = over ? r : sResList[r];
            if (tid == 0) sResPack = ~0ULL;
            __syncthreads();
            const float* zl = &sZf[px * ZSTRIDE]; // same addr all lanes: broadcast
            float zzv = sZZ[px];
            unsigned long long lp = ~0ULL;
            #pragma unroll
            for (int j = 0; j < 4; ++j) {
                int k = tid * 4 + j;
                const float* ek = emb + k * EMB_DIM;
                float acc = 0.f;
                #pragma unroll 8
                for (int c = 0; c < EMB_DIM; ++c)
                    acc = fmaf(ek[c], zl[c], acc);
                float v = (zzv + sE2[k]) - 2.0f * acc;
                unsigned long long p = packvk(v, k);
                lp = p < lp ? p : lp;
            }
            atomicMin(&sResPack, lp);
            __syncthreads();
            if (tid == 0) sBest[px] = (int)(sResPack & 0xFFFFFFFFull);
        }
    }
    __syncthreads();                               // B4

    // ===== enc + epilogue (z from LDS; coalesced z_q stores) =====
    if (tid < 64) enc_out[p0 + tid] = (float)sBest[tid];
    {
        const int px = lane;
        int bestk = sBest[px];
        const float* eq = emb + bestk * EMB_DIM;
        const float* zl = &sZf[px * ZSTRIDE];
        float* op = zq_out + (size_t)b * (EMB_DIM * 4096) + hw0 + px;
        float ls = 0.f;
        #pragma unroll
        for (int j = 0; j < 16; ++j) {
            int c = 16 * w + j;
            float qv = eq[c];
            float d = qv - zl[c];
            ls = fmaf(d, d, ls);
            op[(size_t)c * 4096] = qv;
        }
        #pragma unroll
        for (int off = 32; off > 0; off >>= 1) ls += __shfl_down(ls, off, 64);
        if (lane == 0) atomicAdd(&wsAcc[blockIdx.x & (NACC - 1)], ls);
    }
}

__global__ void vq_final_ws(const float* __restrict__ wsAcc,
                            float* __restrict__ loss_out) {
    int lane = threadIdx.x;                       // 64 threads
    float v = wsAcc[lane];
    #pragma unroll
    for (int off = 32; off > 0; off >>= 1) v += __shfl_down(v, off, 64);
    if (lane == 0) loss_out[0] = v * (1.25f / (float)ZQ_ELEMS);
}

__global__ void vq_final_direct(float* __restrict__ loss_out) {
    loss_out[0] = loss_out[0] * (1.25f / (float)ZQ_ELEMS);
}

// ---------- fallback (round-6 passing kernel) if d_ws is too small ----------
__global__ __launch_bounds__(256) void vq_nn_fb(const float* __restrict__ z_e,
                                                const float* __restrict__ emb,
                                                float* __restrict__ zq_out,
                                                float* __restrict__ enc_out,
                                                float* __restrict__ loss_acc) {
    #pragma clang fp contract(off)
    __shared__ float s_e2[NUM_EMB];
    int tid = threadIdx.x;
    for (int k = tid; k < NUM_EMB; k += 256) s_e2[k] = np_sumsq64(emb + k * EMB_DIM);
    __syncthreads();
    int p = blockIdx.x * 256 + tid;
    int b = p >> 12, hw = p & 4095;
    const float* zp = z_e + (size_t)b * (EMB_DIM * 4096) + hw;
    float z[EMB_DIM];
    #pragma unroll
    for (int c = 0; c < EMB_DIM; ++c) z[c] = zp[(size_t)c * 4096];
    float zz = np_sumsq64(z);
    float b1 = 3.4e38f; int i1 = 0;
    #pragma unroll 2
    for (int k = 0; k < NUM_EMB; ++k) {
        const float* ek = emb + k * EMB_DIM;
        float acc = 0.f;
        #pragma unroll
        for (int c = 0; c < EMB_DIM; ++c) acc = fmaf(ek[c], z[c], acc);
        float sc = (zz + s_e2[k]) - 2.0f * acc;
        bool lt = sc < b1; b1 = lt ? sc : b1; i1 = lt ? k : i1;
    }
    const float* eq = emb + i1 * EMB_DIM;
    float* op = zq_out + (size_t)b * (EMB_DIM * 4096) + hw;
    float ls = 0.f;
    #pragma unroll
    for (int c = 0; c < EMB_DIM; ++c) {
        float q = eq[c]; float d = q - z[c];
        ls = fmaf(d, d, ls);
        op[(size_t)c * 4096] = q;
    }
    enc_out[p] = (float)i1;
    #pragma unroll
    for (int off = 32; off > 0; off >>= 1) ls += __shfl_down(ls, off, 64);
    if ((tid & 63) == 0) atomicAdd(loss_acc, ls);
}

extern "C" void kernel_launch(void* const* d_in, const int* in_sizes, int n_in,
                              void* d_out, int out_size, void* d_ws, size_t ws_size,
                              hipStream_t stream) {
    const float* z_e = (const float*)d_in[0];
    const float* emb = (const float*)d_in[1];
    float* out = (float*)d_out;
    float* loss_out = out + ZQ_ELEMS;
    float* enc_out  = out + ZQ_ELEMS + 1;

    if (ws_size >= 140 * 1024) {
        short* wsE   = (short*)d_ws;                       // 128 KB frag-order
        float* wsE2  = (float*)((char*)d_ws + 131072);     // 4 KB
        float* wsAcc = (float*)((char*)d_ws + 135168);     // 256 B
        vq_zero_ws<<<1, NACC, 0, stream>>>(loss_out, wsAcc);
        vq_prep<<<16, 256, 0, stream>>>(emb, wsE, wsE2);
        vq_mfma<<<NPIX / 64, 256, 0, stream>>>(z_e, emb, wsE, wsE2, out, enc_out, wsAcc);
        vq_final_ws<<<1, 64, 0, stream>>>(wsAcc, loss_out);
    } else {
        hipMemsetAsync(loss_out, 0, 4, stream);
        vq_nn_fb<<<NPIX / 256, 256, 0, stream>>>(z_e, emb, out, enc_out, loss_out);
        vq_final_direct<<<1, 1, 0, stream>>>(loss_out);
    }
}

// Round 12
// 118.097 us; speedup vs baseline: 8.8569x; 8.8569x over previous
//
#include <hip/hip_runtime.h>
#include <hip/hip_bf16.h>

#define NUM_EMB 1024
#define EMB_DIM 64
#define NPIX    131072                 // 32*64*64 pixels
#define ZQ_ELEMS 8388608               // NPIX * EMB_DIM
#define KDEPTH  16
#define ZSTRIDE 65                     // padded f32 LDS stride (conflict-free)
#define NACC    64                     // spread loss accumulators

// d_out FLOAT32: [ z_q (8388608, b-c-h-w) | loss (1) | enc (131072) ]
// d_ws: [ E'frag 128KB | e2 f32 4KB | lossAcc f32[64] @135168 ]

typedef __attribute__((ext_vector_type(8))) short short8_t;  // bf16x8 frag
typedef __attribute__((ext_vector_type(4))) float f32x4;     // mfma acc

__global__ void vq_zero_ws(float* __restrict__ loss_out, float* __restrict__ wsAcc) {
    if (threadIdx.x == 0) loss_out[0] = 0.f;
    wsAcc[threadIdx.x] = 0.f;          // 64 threads
}

// numpy pairwise-sum (n=64, 8-accumulator) of x[j]^2 — token-identical to the
// round-5..10 PASSING kernels (bit-matches np.sum(x**2, axis=-1)).
__device__ __forceinline__ float np_sumsq64(const float* __restrict__ x) {
    float q[EMB_DIM];
    #pragma unroll
    for (int c = 0; c < EMB_DIM; ++c) q[c] = x[c] * x[c];
    float r0 = q[0], r1 = q[1], r2 = q[2], r3 = q[3];
    float r4 = q[4], r5 = q[5], r6 = q[6], r7 = q[7];
    #pragma unroll
    for (int g = 1; g < 8; ++g) {
        r0 += q[8 * g + 0]; r1 += q[8 * g + 1];
        r2 += q[8 * g + 2]; r3 += q[8 * g + 3];
        r4 += q[8 * g + 4]; r5 += q[8 * g + 5];
        r6 += q[8 * g + 6]; r7 += q[8 * g + 7];
    }
    return ((r0 + r1) + (r2 + r3)) + ((r4 + r5) + (r6 + r7));
}

__device__ __forceinline__ unsigned long long packvk(float v, int k) {
    unsigned u = __float_as_uint(v);
    u = (u & 0x80000000u) ? ~u : (u | 0x80000000u);   // monotonic f32 -> u32
    return ((unsigned long long)u << 32) | (unsigned)k;
}

// Prep: E'frag (swizzled for coalesced A-frag loads) + np-exact e2. (unchanged)
__global__ __launch_bounds__(256) void vq_prep(const float* __restrict__ emb,
                                               short* __restrict__ wsE,
                                               float* __restrict__ wsE2) {
    #pragma clang fp contract(off)
    int t    = blockIdx.x * 256 + threadIdx.x;    // grid = 16 x 256 = 4096
    int l    = t & 63;
    int ch   = (t >> 6) & 15;
    int q    = t >> 10;
    int code = q * 256 + ch * 16 + (l & 15);
    const float* ek = emb + code * EMB_DIM;
    #pragma unroll
    for (int h = 0; h < 2; ++h) {
        short8_t pk;
        #pragma unroll
        for (int j = 0; j < 8; ++j) {
            int chan = 32 * h + 8 * (l >> 4) + j;
            __hip_bfloat16 bv = __float2bfloat16(-2.0f * ek[chan]);
            unsigned short u; __builtin_memcpy(&u, &bv, 2);
            pk[j] = (short)u;
        }
        *(short8_t*)(wsE + t * 16 + h * 8) = pk;
    }
    if (t < NUM_EMB) wsE2[t] = np_sumsq64(emb + t * EMB_DIM);
}

// ---------------------------------------------------------------------------
// Main (round-10 structure, verified): 4 waves x 64 px/block; wave w screens
// quarter w. Pass A: MFMA min (C-init=e2). Pass B: recompute + band-collect
// into per-pixel lists. Eval: exact np-f32, 4 threads/pixel, atomicMin pack.
// Deltas vs r10: launch_bounds(256,6); 2-deep A-frag prefetch in both passes.
// ---------------------------------------------------------------------------
__global__ __launch_bounds__(256, 6) void vq_mfma(const float* __restrict__ z_e,
                                                  const float* __restrict__ emb,
                                                  const short* __restrict__ wsE,
                                                  const float* __restrict__ wsE2,
                                                  float* __restrict__ zq_out,
                                                  float* __restrict__ enc_out,
                                                  float* __restrict__ wsAcc) {
    #pragma clang fp contract(off)
    __shared__ float sZf[64 * ZSTRIDE];           // 16.6 KB exact f32 z tile
    __shared__ float sE2[NUM_EMB];                // 4 KB
    __shared__ float sMin[4][64];                 // 1 KB
    __shared__ float sBand[64];
    __shared__ float sThr[64];
    __shared__ float sZZ[64];
    __shared__ unsigned long long sBestPack[64];  // (mono(v)<<32)|k
    __shared__ unsigned short sKbuf[64][KDEPTH];  // 2 KB
    __shared__ int   sKcnt[64];

    const int tid  = threadIdx.x;
    const int w    = tid >> 6;
    const int lane = tid & 63;
    const int p0   = blockIdx.x * 64;
    const int b    = p0 >> 12;                    // uniform (64 | 4096)
    const int hw0  = p0 & 4095;
    const float* base = z_e + (size_t)b * (EMB_DIM * 4096) + hw0;

    *(f32x4*)&sE2[tid * 4] = *(const f32x4*)&wsE2[tid * 4];
    if (tid < 64) { sKcnt[tid] = 0; sBestPack[tid] = ~0ULL; }

    // --- tile load: thread -> pixel lane, channels 16w..16w+15 (coalesced) ---
    {
        const float* zp = base + lane;
        float v[16];
        #pragma unroll
        for (int j = 0; j < 16; ++j) v[j] = zp[(size_t)(16 * w + j) * 4096];
        #pragma unroll
        for (int j = 0; j < 16; ++j) sZf[lane * ZSTRIDE + 16 * w + j] = v[j];
    }
    __syncthreads();

    // --- wave0: np-exact zz + band from LDS (overlaps other waves) ---
    if (w == 0) {
        const float* zl = &sZf[lane * ZSTRIDE];
        float rr[8] = {0,0,0,0,0,0,0,0};
        float sab = 0.f;
        #pragma unroll
        for (int g = 0; g < 8; ++g)
            #pragma unroll
            for (int j = 0; j < 8; ++j) {
                float zc = zl[8 * g + j];
                float qq = zc * zc;               // separate mul (contract off)
                rr[j] += qq;                      // g-ascending per j = np order
                sab += fabsf(zc);
            }
        sZZ[lane]   = ((rr[0] + rr[1]) + (rr[2] + rr[3])) + ((rr[4] + rr[5]) + (rr[6] + rr[7]));
        sBand[lane] = 2.0f * (9e-6f * sab + 2e-5f);
    }

    // --- B fragments from f32 LDS, then PIN in VGPRs (no LDS remat) ---
    short8_t bfrag[4][2];
    #pragma unroll
    for (int pg = 0; pg < 4; ++pg)
        #pragma unroll
        for (int h = 0; h < 2; ++h) {
            int bpr = pg * 16 + (lane & 15);
            int c0  = 32 * h + 8 * (lane >> 4);
            short8_t pk;
            #pragma unroll
            for (int j = 0; j < 8; ++j) {
                __hip_bfloat16 bv = __float2bfloat16(sZf[bpr * ZSTRIDE + c0 + j]);
                unsigned short u; __builtin_memcpy(&u, &bv, 2);
                pk[j] = (short)u;
            }
            asm volatile("" : "+v"(pk));          // force materialization
            bfrag[pg][h] = pk;
        }

    const short8_t* ef = (const short8_t*)wsE + (size_t)w * 2048;

    // ===== PASS A: per-pixel min (C-init = e2; 2-deep A-frag prefetch) =====
    float m[4] = {1e30f, 1e30f, 1e30f, 1e30f};
    {
        short8_t A0a = ef[(0 * 64 + lane) * 2 + 0];
        short8_t A1a = ef[(0 * 64 + lane) * 2 + 1];
        short8_t A0b = ef[(1 * 64 + lane) * 2 + 0];
        short8_t A1b = ef[(1 * 64 + lane) * 2 + 1];
        #pragma unroll 1
        for (int ch = 0; ch < 16; ch += 2) {
            {   // even: consumes (A0a,A1a), prefetches ch+2
                int chn = ch + 2 < 16 ? ch + 2 : 15;
                short8_t N0 = ef[(chn * 64 + lane) * 2 + 0];
                short8_t N1 = ef[(chn * 64 + lane) * 2 + 1];
                int kbase = w * 256 + ch * 16 + 4 * (lane >> 4);
                f32x4 e2v = *(const f32x4*)(&sE2[kbase]);
                #pragma unroll
                for (int pg = 0; pg < 4; ++pg) {
                    f32x4 acc = e2v;
                    acc = __builtin_amdgcn_mfma_f32_16x16x32_bf16(A0a, bfrag[pg][0], acc, 0, 0, 0);
                    acc = __builtin_amdgcn_mfma_f32_16x16x32_bf16(A1a, bfrag[pg][1], acc, 0, 0, 0);
                    m[pg] = fminf(m[pg], fminf(fminf(acc[0], acc[1]), fminf(acc[2], acc[3])));
                }
                A0a = N0; A1a = N1;
            }
            {   // odd: consumes (A0b,A1b), prefetches ch+3
                int chn = ch + 3 < 16 ? ch + 3 : 15;
                short8_t N0 = ef[(chn * 64 + lane) * 2 + 0];
                short8_t N1 = ef[(chn * 64 + lane) * 2 + 1];
                int kbase = w * 256 + (ch + 1) * 16 + 4 * (lane >> 4);
                f32x4 e2v = *(const f32x4*)(&sE2[kbase]);
                #pragma unroll
                for (int pg = 0; pg < 4; ++pg) {
                    f32x4 acc = e2v;
                    acc = __builtin_amdgcn_mfma_f32_16x16x32_bf16(A0b, bfrag[pg][0], acc, 0, 0, 0);
                    acc = __builtin_amdgcn_mfma_f32_16x16x32_bf16(A1b, bfrag[pg][1], acc, 0, 0, 0);
                    m[pg] = fminf(m[pg], fminf(fminf(acc[0], acc[1]), fminf(acc[2], acc[3])));
                }
                A0b = N0; A1b = N1;
            }
        }
    }
    #pragma unroll
    for (int pg = 0; pg < 4; ++pg) {
        m[pg] = fminf(m[pg], __shfl_xor(m[pg], 16, 64));
        m[pg] = fminf(m[pg], __shfl_xor(m[pg], 32, 64));
    }
    if (lane < 16) {
        #pragma unroll
        for (int pg = 0; pg < 4; ++pg) sMin[w][pg * 16 + lane] = m[pg];
    }
    __syncthreads();
    if (tid < 64)
        sThr[tid] = fminf(fminf(sMin[0][tid], sMin[1][tid]),
                          fminf(sMin[2][tid], sMin[3][tid])) + sBand[tid];
    __syncthreads();

    // ===== PASS B: recompute (bit-identical), collect band candidates =====
    {
        float thr[4];
        #pragma unroll
        for (int pg = 0; pg < 4; ++pg) thr[pg] = sThr[pg * 16 + (lane & 15)];
        short8_t A0a = ef[(0 * 64 + lane) * 2 + 0];
        short8_t A1a = ef[(0 * 64 + lane) * 2 + 1];
        short8_t A0b = ef[(1 * 64 + lane) * 2 + 0];
        short8_t A1b = ef[(1 * 64 + lane) * 2 + 1];
        #pragma unroll 1
        for (int ch = 0; ch < 16; ch += 2) {
            {
                int chn = ch + 2 < 16 ? ch + 2 : 15;
                short8_t N0 = ef[(chn * 64 + lane) * 2 + 0];
                short8_t N1 = ef[(chn * 64 + lane) * 2 + 1];
                int kbase = w * 256 + ch * 16 + 4 * (lane >> 4);
                f32x4 e2v = *(const f32x4*)(&sE2[kbase]);
                #pragma unroll
                for (int pg = 0; pg < 4; ++pg) {
                    f32x4 acc = e2v;
                    acc = __builtin_amdgcn_mfma_f32_16x16x32_bf16(A0a, bfrag[pg][0], acc, 0, 0, 0);
                    acc = __builtin_amdgcn_mfma_f32_16x16x32_bf16(A1a, bfrag[pg][1], acc, 0, 0, 0);
                    #pragma unroll
                    for (int j = 0; j < 4; ++j) {
                        if (acc[j] <= thr[pg]) {
                            int pix  = pg * 16 + (lane & 15);
                            int slot = atomicAdd(&sKcnt[pix], 1);
                            if (slot < KDEPTH) sKbuf[pix][slot] = (unsigned short)(kbase + j);
                        }
                    }
                }
                A0a = N0; A1a = N1;
            }
            {
                int chn = ch + 3 < 16 ? ch + 3 : 15;
                short8_t N0 = ef[(chn * 64 + lane) * 2 + 0];
                short8_t N1 = ef[(chn * 64 + lane) * 2 + 1];
                int kbase = w * 256 + (ch + 1) * 16 + 4 * (lane >> 4);
                f32x4 e2v = *(const f32x4*)(&sE2[kbase]);
                #pragma unroll
                for (int pg = 0; pg < 4; ++pg) {
                    f32x4 acc = e2v;
                    acc = __builtin_amdgcn_mfma_f32_16x16x32_bf16(A0b, bfrag[pg][0], acc, 0, 0, 0);
                    acc = __builtin_amdgcn_mfma_f32_16x16x32_bf16(A1b, bfrag[pg][1], acc, 0, 0, 0);
                    #pragma unroll
                    for (int j = 0; j < 4; ++j) {
                        if (acc[j] <= thr[pg]) {
                            int pix  = pg * 16 + (lane & 15);
                            int slot = atomicAdd(&sKcnt[pix], 1);
                            if (slot < KDEPTH) sKbuf[pix][slot] = (unsigned short)(kbase + j);
                        }
                    }
                }
                A0b = N0; A1b = N1;
            }
        }
    }
    __syncthreads();

    // ===== EXACT EVAL: 4 threads/pixel (wave w = slot offset w) =====
    {
        const int px = lane;
        const float* zl = &sZf[px * ZSTRIDE];
        float zzv = sZZ[px];
        int rawcnt = sKcnt[px];
        if (rawcnt <= KDEPTH) {
            for (int s = w; s < rawcnt; s += 4) {
                int k = (int)sKbuf[px][s];
                const float* ek = emb + k * EMB_DIM;
                float acc = 0.f;
                #pragma unroll 8
                for (int c = 0; c < EMB_DIM; ++c)   // sequential fmaf = BLAS order
                    acc = fmaf(ek[c], zl[c], acc);
                float v = (zzv + sE2[k]) - 2.0f * acc;  // exact np token sequence
                atomicMin(&sBestPack[px], packvk(v, k));
            }
        } else {                                   // overflow safety net (~never)
            for (int k = w; k < NUM_EMB; k += 4) {
                const float* ek = emb + k * EMB_DIM;
                float acc = 0.f;
                #pragma unroll 8
                for (int c = 0; c < EMB_DIM; ++c)
                    acc = fmaf(ek[c], zl[c], acc);
                float v = (zzv + sE2[k]) - 2.0f * acc;
                atomicMin(&sBestPack[px], packvk(v, k));
            }
        }
    }
    __syncthreads();

    // ===== enc + epilogue (z from LDS; coalesced z_q stores) =====
    if (tid < 64)
        enc_out[p0 + tid] = (float)(unsigned)(sBestPack[tid] & 0xFFFFFFFFull);
    {
        const int px = lane;
        int bestk = (int)(sBestPack[px] & 0xFFFFFFFFull);
        const float* eq = emb + bestk * EMB_DIM;
        const float* zl = &sZf[px * ZSTRIDE];
        float* op = zq_out + (size_t)b * (EMB_DIM * 4096) + hw0 + px;
        float ls = 0.f;
        #pragma unroll
        for (int j = 0; j < 16; ++j) {
            int c = 16 * w + j;
            float qv = eq[c];
            float d = qv - zl[c];
            ls = fmaf(d, d, ls);
            op[(size_t)c * 4096] = qv;
        }
        #pragma unroll
        for (int off = 32; off > 0; off >>= 1) ls += __shfl_down(ls, off, 64);
        if (lane == 0) atomicAdd(&wsAcc[blockIdx.x & (NACC - 1)], ls);
    }
}

__global__ void vq_final_ws(const float* __restrict__ wsAcc,
                            float* __restrict__ loss_out) {
    int lane = threadIdx.x;                       // 64 threads
    float v = wsAcc[lane];
    #pragma unroll
    for (int off = 32; off > 0; off >>= 1) v += __shfl_down(v, off, 64);
    if (lane == 0) loss_out[0] = v * (1.25f / (float)ZQ_ELEMS);
}

__global__ void vq_final_direct(float* __restrict__ loss_out) {
    loss_out[0] = loss_out[0] * (1.25f / (float)ZQ_ELEMS);
}

// ---------- fallback (round-6 passing kernel) if d_ws is too small ----------
__global__ __launch_bounds__(256) void vq_nn_fb(const float* __restrict__ z_e,
                                                const float* __restrict__ emb,
                                                float* __restrict__ zq_out,
                                                float* __restrict__ enc_out,
                                                float* __restrict__ loss_acc) {
    #pragma clang fp contract(off)
    __shared__ float s_e2[NUM_EMB];
    int tid = threadIdx.x;
    for (int k = tid; k < NUM_EMB; k += 256) s_e2[k] = np_sumsq64(emb + k * EMB_DIM);
    __syncthreads();
    int p = blockIdx.x * 256 + tid;
    int b = p >> 12, hw = p & 4095;
    const float* zp = z_e + (size_t)b * (EMB_DIM * 4096) + hw;
    float z[EMB_DIM];
    #pragma unroll
    for (int c = 0; c < EMB_DIM; ++c) z[c] = zp[(size_t)c * 4096];
    float zz = np_sumsq64(z);
    float b1 = 3.4e38f; int i1 = 0;
    #pragma unroll 2
    for (int k = 0; k < NUM_EMB; ++k) {
        const float* ek = emb + k * EMB_DIM;
        float acc = 0.f;
        #pragma unroll
        for (int c = 0; c < EMB_DIM; ++c) acc = fmaf(ek[c], z[c], acc);
        float sc = (zz + s_e2[k]) - 2.0f * acc;
        bool lt = sc < b1; b1 = lt ? sc : b1; i1 = lt ? k : i1;
    }
    const float* eq = emb + i1 * EMB_DIM;
    float* op = zq_out + (size_t)b * (EMB_DIM * 4096) + hw;
    float ls = 0.f;
    #pragma unroll
    for (int c = 0; c < EMB_DIM; ++c) {
        float q = eq[c]; float d = q - z[c];
        ls = fmaf(d, d, ls);
        op[(size_t)c * 4096] = q;
    }
    enc_out[p] = (float)i1;
    #pragma unroll
    for (int off = 32; off > 0; off >>= 1) ls += __shfl_down(ls, off, 64);
    if ((tid & 63) == 0) atomicAdd(loss_acc, ls);
}

extern "C" void kernel_launch(void* const* d_in, const int* in_sizes, int n_in,
                              void* d_out, int out_size, void* d_ws, size_t ws_size,
                              hipStream_t stream) {
    const float* z_e = (const float*)d_in[0];
    const float* emb = (const float*)d_in[1];
    float* out = (float*)d_out;
    float* loss_out = out + ZQ_ELEMS;
    float* enc_out  = out + ZQ_ELEMS + 1;

    if (ws_size >= 140 * 1024) {
        short* wsE   = (short*)d_ws;                       // 128 KB frag-order
        float* wsE2  = (float*)((char*)d_ws + 131072);     // 4 KB
        float* wsAcc = (float*)((char*)d_ws + 135168);     // 256 B
        vq_zero_ws<<<1, NACC, 0, stream>>>(loss_out, wsAcc);
        vq_prep<<<16, 256, 0, stream>>>(emb, wsE, wsE2);
        vq_mfma<<<NPIX / 64, 256, 0, stream>>>(z_e, emb, wsE, wsE2, out, enc_out, wsAcc);
        vq_final_ws<<<1, 64, 0, stream>>>(wsAcc, loss_out);
    } else {
        hipMemsetAsync(loss_out, 0, 4, stream);
        vq_nn_fb<<<NPIX / 256, 256, 0, stream>>>(z_e, emb, out, enc_out, loss_out);
        vq_final_direct<<<1, 1, 0, stream>>>(loss_out);
    }
}

// Round 13
// 111.259 us; speedup vs baseline: 9.4013x; 1.0615x over previous
//
#include <hip/hip_runtime.h>
#include <hip/hip_bf16.h>

#define NUM_EMB 1024
#define EMB_DIM 64
#define NPIX    131072                 // 32*64*64 pixels
#define ZQ_ELEMS 8388608               // NPIX * EMB_DIM
#define KDEPTH  16
#define ZSTRIDE 65                     // padded f32 LDS stride (conflict-free)
#define NACC    64                     // spread loss accumulators
#define NCHUNK  32                     // 32 chunks x 32 codes (4 KB each)
#define CHUNK_SH 2048                  // shorts per chunk

// d_out FLOAT32: [ z_q (8388608, b-c-h-w) | loss (1) | enc (131072) ]
// d_ws: [ E'frag 128KB (chunk,ch,half,lane order) | e2 f32 4KB | lossAcc @135168 ]

typedef __attribute__((ext_vector_type(8))) short short8_t;  // bf16x8 frag
typedef __attribute__((ext_vector_type(4))) float f32x4;     // mfma acc

__global__ void vq_zero_ws(float* __restrict__ loss_out, float* __restrict__ wsAcc) {
    if (threadIdx.x == 0) loss_out[0] = 0.f;
    wsAcc[threadIdx.x] = 0.f;          // 64 threads
}

// numpy pairwise-sum (n=64, 8-accumulator) of x[j]^2 — token-identical to the
// round-5..12 PASSING kernels (bit-matches np.sum(x**2, axis=-1)).
__device__ __forceinline__ float np_sumsq64(const float* __restrict__ x) {
    float q[EMB_DIM];
    #pragma unroll
    for (int c = 0; c < EMB_DIM; ++c) q[c] = x[c] * x[c];
    float r0 = q[0], r1 = q[1], r2 = q[2], r3 = q[3];
    float r4 = q[4], r5 = q[5], r6 = q[6], r7 = q[7];
    #pragma unroll
    for (int g = 1; g < 8; ++g) {
        r0 += q[8 * g + 0]; r1 += q[8 * g + 1];
        r2 += q[8 * g + 2]; r3 += q[8 * g + 3];
        r4 += q[8 * g + 4]; r5 += q[8 * g + 5];
        r6 += q[8 * g + 6]; r7 += q[8 * g + 7];
    }
    return ((r0 + r1) + (r2 + r3)) + ((r4 + r5) + (r6 + r7));
}

__device__ __forceinline__ unsigned long long packvk(float v, int k) {
    unsigned u = __float_as_uint(v);
    u = (u & 0x80000000u) ? ~u : (u | 0x80000000u);   // monotonic f32 -> u32
    return ((unsigned long long)u << 32) | (unsigned)k;
}

// Prep: E'frag in (chunk, ch16, half, lane) order so chunk staging is a linear
// 4KB copy and per-lane ds_read_b128 is lane-consecutive. Same frag contents
// as rounds 7-12 (code = C16*16 + (l&15), chan = 32h + 8*(l>>4) + j).
__global__ __launch_bounds__(256) void vq_prep(const float* __restrict__ emb,
                                               short* __restrict__ wsE,
                                               float* __restrict__ wsE2) {
    #pragma clang fp contract(off)
    int t   = blockIdx.x * 256 + threadIdx.x;     // grid = 16 x 256 = 4096
    int l   = t & 63;
    int C16 = t >> 6;                             // 16-code group 0..63
    int code = C16 * 16 + (l & 15);
    const float* ek = emb + code * EMB_DIM;
    #pragma unroll
    for (int h = 0; h < 2; ++h) {
        short8_t pk;
        #pragma unroll
        for (int j = 0; j < 8; ++j) {
            int chan = 32 * h + 8 * (l >> 4) + j;
            __hip_bfloat16 bv = __float2bfloat16(-2.0f * ek[chan]);
            unsigned short u; __builtin_memcpy(&u, &bv, 2);
            pk[j] = (short)u;
        }
        int so = (C16 >> 1) * CHUNK_SH + (((C16 & 1) * 2 + h) * 64 + l) * 8;
        *(short8_t*)(wsE + so) = pk;
    }
    if (t < NUM_EMB) wsE2[t] = np_sumsq64(emb + t * EMB_DIM);
}

// ---------------------------------------------------------------------------
// Main: 4 waves x 64 px/block, PIXEL-split: wave w owns pixels w*16..w*16+15
// over ALL 1024 codes. Codebook streamed through a double-buffered 4KB LDS
// chunk shared by all waves (T14 reg-staged split: load early, ds_write late).
// Pass A: MFMA min (C-init=e2). Pass B: recompute + band-collect (thr wave-
// local). Eval/epilogue: exact np-f32, 4 threads/pixel (r10 verbatim).
// ---------------------------------------------------------------------------
__global__ __launch_bounds__(256, 4) void vq_mfma(const float* __restrict__ z_e,
                                                  const float* __restrict__ emb,
                                                  const short* __restrict__ wsE,
                                                  const float* __restrict__ wsE2,
                                                  float* __restrict__ zq_out,
                                                  float* __restrict__ enc_out,
                                                  float* __restrict__ wsAcc) {
    #pragma clang fp contract(off)
    __shared__ float sZf[64 * ZSTRIDE];           // 16.6 KB exact f32 z tile
    __shared__ float sE2[NUM_EMB];                // 4 KB
    __shared__ short sChunk[2][CHUNK_SH];         // 8 KB dbuf frag chunks
    __shared__ float sBand[64];
    __shared__ float sZZ[64];
    __shared__ unsigned long long sBestPack[64];  // (mono(v)<<32)|k
    __shared__ unsigned short sKbuf[64][KDEPTH];  // 2 KB
    __shared__ int   sKcnt[64];

    const int tid  = threadIdx.x;
    const int w    = tid >> 6;
    const int lane = tid & 63;
    const int p0   = blockIdx.x * 64;
    const int b    = p0 >> 12;                    // uniform (64 | 4096)
    const int hw0  = p0 & 4095;
    const float* base = z_e + (size_t)b * (EMB_DIM * 4096) + hw0;
    const int myPx = w * 16 + (lane & 15);        // wave-owned pixel

    *(f32x4*)&sE2[tid * 4] = *(const f32x4*)&wsE2[tid * 4];
    if (tid < 64) { sKcnt[tid] = 0; sBestPack[tid] = ~0ULL; }

    // --- tile load: thread -> pixel lane, channels 16w..16w+15 (coalesced) ---
    {
        const float* zp = base + lane;
        float v[16];
        #pragma unroll
        for (int j = 0; j < 16; ++j) v[j] = zp[(size_t)(16 * w + j) * 4096];
        #pragma unroll
        for (int j = 0; j < 16; ++j) sZf[lane * ZSTRIDE + 16 * w + j] = v[j];
    }
    __syncthreads();                               // B1: sZf ready

    // --- issue chunk-0 stage load EARLY (hides under zz/bfrag work) ---
    short8_t vs0 = *(const short8_t*)(wsE + tid * 8);

    // --- np-exact zz + band for my pixel (all lanes active, 4x redundant) ---
    {
        const float* zl = &sZf[myPx * ZSTRIDE];
        float rr[8] = {0,0,0,0,0,0,0,0};
        float sab = 0.f;
        #pragma unroll
        for (int g = 0; g < 8; ++g)
            #pragma unroll
            for (int j = 0; j < 8; ++j) {
                float zc = zl[8 * g + j];
                float qq = zc * zc;               // separate mul (contract off)
                rr[j] += qq;                      // g-ascending per j = np order
                sab += fabsf(zc);
            }
        if (lane < 16) {
            sZZ[myPx]   = ((rr[0] + rr[1]) + (rr[2] + rr[3])) + ((rr[4] + rr[5]) + (rr[6] + rr[7]));
            sBand[myPx] = 2.0f * (9e-6f * sab + 2e-5f);
        }
    }

    // --- B fragments for MY pixel group only (8 VGPRs), pinned ---
    short8_t bf0, bf1;
    {
        int bpr = w * 16 + (lane & 15);
        #pragma unroll
        for (int h = 0; h < 2; ++h) {
            int c0 = 32 * h + 8 * (lane >> 4);
            short8_t pk;
            #pragma unroll
            for (int j = 0; j < 8; ++j) {
                __hip_bfloat16 bv = __float2bfloat16(sZf[bpr * ZSTRIDE + c0 + j]);
                unsigned short u; __builtin_memcpy(&u, &bv, 2);
                pk[j] = (short)u;
            }
            asm volatile("" : "+v"(pk));          // force materialization
            if (h == 0) bf0 = pk; else bf1 = pk;
        }
    }

    // write chunk 0, publish
    *(short8_t*)&sChunk[0][tid * 8] = vs0;
    __syncthreads();                               // B2: chunk 0 ready

    // ===== PASS A: per-pixel min over all codes, dbuf chunk pipeline =====
    float m = 1e30f;
    int cur = 0;
    #pragma unroll 1
    for (int c = 0; c < NCHUNK; ++c) {
        short8_t vs;
        const bool more = (c + 1 < NCHUNK);
        if (more) vs = *(const short8_t*)(wsE + (c + 1) * CHUNK_SH + tid * 8);
        #pragma unroll
        for (int chl = 0; chl < 2; ++chl) {
            short8_t A0 = *(const short8_t*)&sChunk[cur][((chl * 2 + 0) * 64 + lane) * 8];
            short8_t A1 = *(const short8_t*)&sChunk[cur][((chl * 2 + 1) * 64 + lane) * 8];
            int kbase = (c * 2 + chl) * 16 + 4 * (lane >> 4);
            f32x4 e2v = *(const f32x4*)(&sE2[kbase]);
            f32x4 acc = e2v;
            acc = __builtin_amdgcn_mfma_f32_16x16x32_bf16(A0, bf0, acc, 0, 0, 0);
            acc = __builtin_amdgcn_mfma_f32_16x16x32_bf16(A1, bf1, acc, 0, 0, 0);
            m = fminf(m, fminf(fminf(acc[0], acc[1]), fminf(acc[2], acc[3])));
        }
        if (more) *(short8_t*)&sChunk[cur ^ 1][tid * 8] = vs;
        __syncthreads();
        cur ^= 1;
    }

    // wave-local per-pixel min + threshold (no cross-wave merge needed)
    m = fminf(m, __shfl_xor(m, 16, 64));
    m = fminf(m, __shfl_xor(m, 32, 64));
    const float thr = m + sBand[myPx];

    // ===== PASS B: recompute (bit-identical), collect band candidates =====
    {
        short8_t vsb = *(const short8_t*)(wsE + tid * 8);
        *(short8_t*)&sChunk[0][tid * 8] = vsb;     // buf0 free since c=30's barrier
    }
    __syncthreads();
    cur = 0;
    #pragma unroll 1
    for (int c = 0; c < NCHUNK; ++c) {
        short8_t vs;
        const bool more = (c + 1 < NCHUNK);
        if (more) vs = *(const short8_t*)(wsE + (c + 1) * CHUNK_SH + tid * 8);
        #pragma unroll
        for (int chl = 0; chl < 2; ++chl) {
            short8_t A0 = *(const short8_t*)&sChunk[cur][((chl * 2 + 0) * 64 + lane) * 8];
            short8_t A1 = *(const short8_t*)&sChunk[cur][((chl * 2 + 1) * 64 + lane) * 8];
            int kbase = (c * 2 + chl) * 16 + 4 * (lane >> 4);
            f32x4 e2v = *(const f32x4*)(&sE2[kbase]);
            f32x4 acc = e2v;
            acc = __builtin_amdgcn_mfma_f32_16x16x32_bf16(A0, bf0, acc, 0, 0, 0);
            acc = __builtin_amdgcn_mfma_f32_16x16x32_bf16(A1, bf1, acc, 0, 0, 0);
            #pragma unroll
            for (int j = 0; j < 4; ++j) {
                if (acc[j] <= thr) {
                    int slot = atomicAdd(&sKcnt[myPx], 1);
                    if (slot < KDEPTH) sKbuf[myPx][slot] = (unsigned short)(kbase + j);
                }
            }
        }
        if (more) *(short8_t*)&sChunk[cur ^ 1][tid * 8] = vs;
        __syncthreads();
        cur ^= 1;
    }

    // ===== EXACT EVAL: 4 threads/pixel (wave w = slot offset w) — r10 =====
    {
        const int px = lane;
        const float* zl = &sZf[px * ZSTRIDE];
        float zzv = sZZ[px];
        int rawcnt = sKcnt[px];
        if (rawcnt <= KDEPTH) {
            for (int s = w; s < rawcnt; s += 4) {
                int k = (int)sKbuf[px][s];
                const float* ek = emb + k * EMB_DIM;
                float acc = 0.f;
                #pragma unroll 8
                for (int c = 0; c < EMB_DIM; ++c)   // sequential fmaf = BLAS order
                    acc = fmaf(ek[c], zl[c], acc);
                float v = (zzv + sE2[k]) - 2.0f * acc;  // exact np token sequence
                atomicMin(&sBestPack[px], packvk(v, k));
            }
        } else {                                   // overflow safety net (~never)
            for (int k = w; k < NUM_EMB; k += 4) {
                const float* ek = emb + k * EMB_DIM;
                float acc = 0.f;
                #pragma unroll 8
                for (int c = 0; c < EMB_DIM; ++c)
                    acc = fmaf(ek[c], zl[c], acc);
                float v = (zzv + sE2[k]) - 2.0f * acc;
                atomicMin(&sBestPack[px], packvk(v, k));
            }
        }
    }
    __syncthreads();

    // ===== enc + epilogue (z from LDS; coalesced z_q stores) — r10 =====
    if (tid < 64)
        enc_out[p0 + tid] = (float)(unsigned)(sBestPack[tid] & 0xFFFFFFFFull);
    {
        const int px = lane;
        int bestk = (int)(sBestPack[px] & 0xFFFFFFFFull);
        const float* eq = emb + bestk * EMB_DIM;
        const float* zl = &sZf[px * ZSTRIDE];
        float* op = zq_out + (size_t)b * (EMB_DIM * 4096) + hw0 + px;
        float ls = 0.f;
        #pragma unroll
        for (int j = 0; j < 16; ++j) {
            int c = 16 * w + j;
            float qv = eq[c];
            float d = qv - zl[c];
            ls = fmaf(d, d, ls);
            op[(size_t)c * 4096] = qv;
        }
        #pragma unroll
        for (int off = 32; off > 0; off >>= 1) ls += __shfl_down(ls, off, 64);
        if (lane == 0) atomicAdd(&wsAcc[blockIdx.x & (NACC - 1)], ls);
    }
}

__global__ void vq_final_ws(const float* __restrict__ wsAcc,
                            float* __restrict__ loss_out) {
    int lane = threadIdx.x;                       // 64 threads
    float v = wsAcc[lane];
    #pragma unroll
    for (int off = 32; off > 0; off >>= 1) v += __shfl_down(v, off, 64);
    if (lane == 0) loss_out[0] = v * (1.25f / (float)ZQ_ELEMS);
}

__global__ void vq_final_direct(float* __restrict__ loss_out) {
    loss_out[0] = loss_out[0] * (1.25f / (float)ZQ_ELEMS);
}

// ---------- fallback (round-6 passing kernel) if d_ws is too small ----------
__global__ __launch_bounds__(256) void vq_nn_fb(const float* __restrict__ z_e,
                                                const float* __restrict__ emb,
                                                float* __restrict__ zq_out,
                                                float* __restrict__ enc_out,
                                                float* __restrict__ loss_acc) {
    #pragma clang fp contract(off)
    __shared__ float s_e2[NUM_EMB];
    int tid = threadIdx.x;
    for (int k = tid; k < NUM_EMB; k += 256) s_e2[k] = np_sumsq64(emb + k * EMB_DIM);
    __syncthreads();
    int p = blockIdx.x * 256 + tid;
    int b = p >> 12, hw = p & 4095;
    const float* zp = z_e + (size_t)b * (EMB_DIM * 4096) + hw;
    float z[EMB_DIM];
    #pragma unroll
    for (int c = 0; c < EMB_DIM; ++c) z[c] = zp[(size_t)c * 4096];
    float zz = np_sumsq64(z);
    float b1 = 3.4e38f; int i1 = 0;
    #pragma unroll 2
    for (int k = 0; k < NUM_EMB; ++k) {
        const float* ek = emb + k * EMB_DIM;
        float acc = 0.f;
        #pragma unroll
        for (int c = 0; c < EMB_DIM; ++c) acc = fmaf(ek[c], z[c], acc);
        float sc = (zz + s_e2[k]) - 2.0f * acc;
        bool lt = sc < b1; b1 = lt ? sc : b1; i1 = lt ? k : i1;
    }
    const float* eq = emb + i1 * EMB_DIM;
    float* op = zq_out + (size_t)b * (EMB_DIM * 4096) + hw;
    float ls = 0.f;
    #pragma unroll
    for (int c = 0; c < EMB_DIM; ++c) {
        float q = eq[c]; float d = q - z[c];
        ls = fmaf(d, d, ls);
        op[(size_t)c * 4096] = q;
    }
    enc_out[p] = (float)i1;
    #pragma unroll
    for (int off = 32; off > 0; off >>= 1) ls += __shfl_down(ls, off, 64);
    if ((tid & 63) == 0) atomicAdd(loss_acc, ls);
}

extern "C" void kernel_launch(void* const* d_in, const int* in_sizes, int n_in,
                              void* d_out, int out_size, void* d_ws, size_t ws_size,
                              hipStream_t stream) {
    const float* z_e = (const float*)d_in[0];
    const float* emb = (const float*)d_in[1];
    float* out = (float*)d_out;
    float* loss_out = out + ZQ_ELEMS;
    float* enc_out  = out + ZQ_ELEMS + 1;

    if (ws_size >= 140 * 1024) {
        short* wsE   = (short*)d_ws;                       // 128 KB frag-order
        float* wsE2  = (float*)((char*)d_ws + 131072);     // 4 KB
        float* wsAcc = (float*)((char*)d_ws + 135168);     // 256 B
        vq_zero_ws<<<1, NACC, 0, stream>>>(loss_out, wsAcc);
        vq_prep<<<16, 256, 0, stream>>>(emb, wsE, wsE2);
        vq_mfma<<<NPIX / 64, 256, 0, stream>>>(z_e, emb, wsE, wsE2, out, enc_out, wsAcc);
        vq_final_ws<<<1, 64, 0, stream>>>(wsAcc, loss_out);
    } else {
        hipMemsetAsync(loss_out, 0, 4, stream);
        vq_nn_fb<<<NPIX / 256, 256, 0, stream>>>(z_e, emb, out, enc_out, loss_out);
        vq_final_direct<<<1, 1, 0, stream>>>(loss_out);
    }
}

// Round 14
// 95.351 us; speedup vs baseline: 10.9697x; 1.1668x over previous
//
#include <hip/hip_runtime.h>
#include <hip/hip_bf16.h>

#define NUM_EMB 1024
#define EMB_DIM 64
#define NPIX    131072                 // 32*64*64 pixels
#define ZQ_ELEMS 8388608               // NPIX * EMB_DIM
#define KDEPTH  16
#define ZSTRIDE 65                     // padded f32 LDS stride (conflict-free)
#define NACC    64                     // spread loss accumulators

// d_out FLOAT32: [ z_q (8388608, b-c-h-w) | loss (1) | enc (131072) ]
// d_ws: [ E'frag 128KB | e2 f32 4KB | lossAcc f32[64] @135168 ]

typedef __attribute__((ext_vector_type(8))) short short8_t;  // bf16x8 frag
typedef __attribute__((ext_vector_type(4))) float f32x4;     // mfma acc

__global__ void vq_zero_ws(float* __restrict__ loss_out, float* __restrict__ wsAcc) {
    if (threadIdx.x == 0) loss_out[0] = 0.f;
    wsAcc[threadIdx.x] = 0.f;          // 64 threads
}

// numpy pairwise-sum (n=64, 8-accumulator) of x[j]^2 — token-identical to the
// round-5..13 PASSING kernels (bit-matches np.sum(x**2, axis=-1)).
__device__ __forceinline__ float np_sumsq64(const float* __restrict__ x) {
    float q[EMB_DIM];
    #pragma unroll
    for (int c = 0; c < EMB_DIM; ++c) q[c] = x[c] * x[c];
    float r0 = q[0], r1 = q[1], r2 = q[2], r3 = q[3];
    float r4 = q[4], r5 = q[5], r6 = q[6], r7 = q[7];
    #pragma unroll
    for (int g = 1; g < 8; ++g) {
        r0 += q[8 * g + 0]; r1 += q[8 * g + 1];
        r2 += q[8 * g + 2]; r3 += q[8 * g + 3];
        r4 += q[8 * g + 4]; r5 += q[8 * g + 5];
        r6 += q[8 * g + 6]; r7 += q[8 * g + 7];
    }
    return ((r0 + r1) + (r2 + r3)) + ((r4 + r5) + (r6 + r7));
}

__device__ __forceinline__ unsigned long long packvk(float v, int k) {
    unsigned u = __float_as_uint(v);
    u = (u & 0x80000000u) ? ~u : (u | 0x80000000u);   // monotonic f32 -> u32
    return ((unsigned long long)u << 32) | (unsigned)k;
}

// Prep: E'frag (swizzled for coalesced A-frag loads) + np-exact e2 (r10 form).
__global__ __launch_bounds__(256) void vq_prep(const float* __restrict__ emb,
                                               short* __restrict__ wsE,
                                               float* __restrict__ wsE2) {
    #pragma clang fp contract(off)
    int t    = blockIdx.x * 256 + threadIdx.x;    // grid = 16 x 256 = 4096
    int l    = t & 63;
    int ch   = (t >> 6) & 15;
    int q    = t >> 10;
    int code = q * 256 + ch * 16 + (l & 15);
    const float* ek = emb + code * EMB_DIM;
    #pragma unroll
    for (int h = 0; h < 2; ++h) {
        short8_t pk;
        #pragma unroll
        for (int j = 0; j < 8; ++j) {
            int chan = 32 * h + 8 * (l >> 4) + j;
            __hip_bfloat16 bv = __float2bfloat16(-2.0f * ek[chan]);
            unsigned short u; __builtin_memcpy(&u, &bv, 2);
            pk[j] = (short)u;
        }
        *(short8_t*)(wsE + t * 16 + h * 8) = pk;
    }
    if (t < NUM_EMB) wsE2[t] = np_sumsq64(emb + t * EMB_DIM);
}

// top-3 insert of (v,kk) for pixel-group pg
#define TOP3_INS(pg, v, kk)                                            \
    {                                                                  \
        bool lt1 = (v) < b1[pg];                                       \
        bool lt2 = (v) < b2[pg];                                       \
        bool lt3 = (v) < b3[pg];                                       \
        b3[pg] = lt2 ? b2[pg] : (lt3 ? (v) : b3[pg]);                  \
        i3[pg] = lt2 ? i2[pg] : (lt3 ? (kk) : i3[pg]);                 \
        b2[pg] = lt1 ? b1[pg] : (lt2 ? (v) : b2[pg]);                  \
        i2[pg] = lt1 ? i1[pg] : (lt2 ? (kk) : i2[pg]);                 \
        b1[pg] = lt1 ? (v) : b1[pg];                                   \
        i1[pg] = lt1 ? (kk) : i1[pg];                                  \
    }

// ---------------------------------------------------------------------------
// Main: r10 skeleton, SINGLE screen pass. Wave w scans quarter w tracking
// per-(lane,pg) top-3. Emit: each lane emits its top-3 entries <= thr into
// sKbuf; if a lane's b3 <= thr the pixel is flagged (lane may have dropped a
// 4th in-band code). Flagged blocks (rare) run the old pass B for flagged
// pixels only. Eval: exact np-f32, 4 threads/pixel; rawcnt==1 shortcut.
// ---------------------------------------------------------------------------
__global__ __launch_bounds__(256, 4) void vq_mfma(const float* __restrict__ z_e,
                                                  const float* __restrict__ emb,
                                                  const short* __restrict__ wsE,
                                                  const float* __restrict__ wsE2,
                                                  float* __restrict__ zq_out,
                                                  float* __restrict__ enc_out,
                                                  float* __restrict__ wsAcc) {
    #pragma clang fp contract(off)
    __shared__ float sZf[64 * ZSTRIDE];           // 16.6 KB exact f32 z tile
    __shared__ float sE2[NUM_EMB];                // 4 KB
    __shared__ float sMin[4][64];                 // 1 KB
    __shared__ float sBand[64];
    __shared__ float sThr[64];
    __shared__ float sZZ[64];
    __shared__ unsigned long long sBestPack[64];  // (mono(v)<<32)|k
    __shared__ unsigned short sKbuf[64][KDEPTH];  // 2 KB
    __shared__ int   sKcnt[64];
    __shared__ int   sPxFlag[64];
    __shared__ int   sFlagAny;

    const int tid  = threadIdx.x;
    const int w    = tid >> 6;
    const int lane = tid & 63;
    const int p0   = blockIdx.x * 64;
    const int b    = p0 >> 12;                    // uniform (64 | 4096)
    const int hw0  = p0 & 4095;
    const float* base = z_e + (size_t)b * (EMB_DIM * 4096) + hw0;

    *(f32x4*)&sE2[tid * 4] = *(const f32x4*)&wsE2[tid * 4];
    if (tid < 64) { sKcnt[tid] = 0; sBestPack[tid] = ~0ULL; sPxFlag[tid] = 0; }
    if (tid == 0) sFlagAny = 0;

    // --- tile load: thread -> pixel lane, channels 16w..16w+15 (coalesced) ---
    {
        const float* zp = base + lane;
        float v[16];
        #pragma unroll
        for (int j = 0; j < 16; ++j) v[j] = zp[(size_t)(16 * w + j) * 4096];
        #pragma unroll
        for (int j = 0; j < 16; ++j) sZf[lane * ZSTRIDE + 16 * w + j] = v[j];
    }
    __syncthreads();                               // B1

    // --- wave0: np-exact zz + band from LDS (overlaps other waves) ---
    if (w == 0) {
        const float* zl = &sZf[lane * ZSTRIDE];
        float rr[8] = {0,0,0,0,0,0,0,0};
        float sab = 0.f;
        #pragma unroll
        for (int g = 0; g < 8; ++g)
            #pragma unroll
            for (int j = 0; j < 8; ++j) {
                float zc = zl[8 * g + j];
                float qq = zc * zc;               // separate mul (contract off)
                rr[j] += qq;                      // g-ascending per j = np order
                sab += fabsf(zc);
            }
        sZZ[lane]   = ((rr[0] + rr[1]) + (rr[2] + rr[3])) + ((rr[4] + rr[5]) + (rr[6] + rr[7]));
        sBand[lane] = 2.0f * (9e-6f * sab + 2e-5f);
    }

    // --- B fragments from f32 LDS, then PIN in VGPRs (no LDS remat) ---
    short8_t bfrag[4][2];
    #pragma unroll
    for (int pg = 0; pg < 4; ++pg)
        #pragma unroll
        for (int h = 0; h < 2; ++h) {
            int bpr = pg * 16 + (lane & 15);
            int c0  = 32 * h + 8 * (lane >> 4);
            short8_t pk;
            #pragma unroll
            for (int j = 0; j < 8; ++j) {
                __hip_bfloat16 bv = __float2bfloat16(sZf[bpr * ZSTRIDE + c0 + j]);
                unsigned short u; __builtin_memcpy(&u, &bv, 2);
                pk[j] = (short)u;
            }
            asm volatile("" : "+v"(pk));          // force materialization
            bfrag[pg][h] = pk;
        }

    const short8_t* ef = (const short8_t*)wsE + (size_t)w * 2048;

    // ===== SINGLE SCREEN PASS: per-(lane,pg) top-3; 1-deep prefetch =====
    float b1[4] = {1e30f, 1e30f, 1e30f, 1e30f};
    float b2[4] = {1e30f, 1e30f, 1e30f, 1e30f};
    float b3[4] = {1e30f, 1e30f, 1e30f, 1e30f};
    int   i1[4] = {0,0,0,0}, i2[4] = {0,0,0,0}, i3[4] = {0,0,0,0};
    {
        short8_t A0 = ef[lane * 2 + 0];
        short8_t A1 = ef[lane * 2 + 1];
        #pragma unroll 1
        for (int ch = 0; ch < 16; ++ch) {
            int chn = ch < 15 ? ch + 1 : 15;
            short8_t N0 = ef[(chn * 64 + lane) * 2 + 0];
            short8_t N1 = ef[(chn * 64 + lane) * 2 + 1];
            int kbase = w * 256 + ch * 16 + 4 * (lane >> 4);
            f32x4 e2v = *(const f32x4*)(&sE2[kbase]);
            #pragma unroll
            for (int pg = 0; pg < 4; ++pg) {
                f32x4 acc = e2v;
                acc = __builtin_amdgcn_mfma_f32_16x16x32_bf16(A0, bfrag[pg][0], acc, 0, 0, 0);
                acc = __builtin_amdgcn_mfma_f32_16x16x32_bf16(A1, bfrag[pg][1], acc, 0, 0, 0);
                #pragma unroll
                for (int j = 0; j < 4; ++j) TOP3_INS(pg, acc[j], kbase + j);
            }
            A0 = N0; A1 = N1;
        }
    }

    // per-pixel global min (b1 only) across lane-groups, then waves
    {
        float m[4];
        #pragma unroll
        for (int pg = 0; pg < 4; ++pg) {
            m[pg] = b1[pg];
            m[pg] = fminf(m[pg], __shfl_xor(m[pg], 16, 64));
            m[pg] = fminf(m[pg], __shfl_xor(m[pg], 32, 64));
        }
        if (lane < 16) {
            #pragma unroll
            for (int pg = 0; pg < 4; ++pg) sMin[w][pg * 16 + lane] = m[pg];
        }
    }
    __syncthreads();                               // B2
    if (tid < 64)
        sThr[tid] = fminf(fminf(sMin[0][tid], sMin[1][tid]),
                          fminf(sMin[2][tid], sMin[3][tid])) + sBand[tid];
    __syncthreads();                               // B3

    // ===== EMIT: each lane emits its top-3 entries <= thr; flag if b3 <= thr =====
    #pragma unroll
    for (int pg = 0; pg < 4; ++pg) {
        int px  = pg * 16 + (lane & 15);
        float thr = sThr[px];
        if (b1[pg] <= thr) {
            int slot = atomicAdd(&sKcnt[px], 1);
            if (slot < KDEPTH) sKbuf[px][slot] = (unsigned short)i1[pg];
        }
        if (b2[pg] <= thr) {
            int slot = atomicAdd(&sKcnt[px], 1);
            if (slot < KDEPTH) sKbuf[px][slot] = (unsigned short)i2[pg];
        }
        if (b3[pg] <= thr) {                       // lane may have dropped a 4th
            int slot = atomicAdd(&sKcnt[px], 1);
            if (slot < KDEPTH) sKbuf[px][slot] = (unsigned short)i3[pg];
            sPxFlag[px] = 1; sFlagAny = 1;
        }
    }
    __syncthreads();                               // B4

    // ===== RARE: flagged pixels -> full collect (old pass B), gated thr =====
    if (sFlagAny) {
        if (tid < 64 && sPxFlag[tid]) sKcnt[tid] = 0;   // re-collect cleanly
        __syncthreads();
        float thrB[4];
        #pragma unroll
        for (int pg = 0; pg < 4; ++pg) {
            int px = pg * 16 + (lane & 15);
            thrB[pg] = sPxFlag[px] ? sThr[px] : -1e30f;
        }
        short8_t A0 = ef[lane * 2 + 0];
        short8_t A1 = ef[lane * 2 + 1];
        #pragma unroll 1
        for (int ch = 0; ch < 16; ++ch) {
            int chn = ch < 15 ? ch + 1 : 15;
            short8_t N0 = ef[(chn * 64 + lane) * 2 + 0];
            short8_t N1 = ef[(chn * 64 + lane) * 2 + 1];
            int kbase = w * 256 + ch * 16 + 4 * (lane >> 4);
            f32x4 e2v = *(const f32x4*)(&sE2[kbase]);
            #pragma unroll
            for (int pg = 0; pg < 4; ++pg) {
                f32x4 acc = e2v;
                acc = __builtin_amdgcn_mfma_f32_16x16x32_bf16(A0, bfrag[pg][0], acc, 0, 0, 0);
                acc = __builtin_amdgcn_mfma_f32_16x16x32_bf16(A1, bfrag[pg][1], acc, 0, 0, 0);
                #pragma unroll
                for (int j = 0; j < 4; ++j) {
                    if (acc[j] <= thrB[pg]) {
                        int pix  = pg * 16 + (lane & 15);
                        int slot = atomicAdd(&sKcnt[pix], 1);
                        if (slot < KDEPTH) sKbuf[pix][slot] = (unsigned short)(kbase + j);
                    }
                }
            }
            A0 = N0; A1 = N1;
        }
        __syncthreads();
    }

    // ===== EXACT EVAL: 4 threads/pixel; rawcnt==1 certified shortcut =====
    {
        const int px = lane;
        const float* zl = &sZf[px * ZSTRIDE];
        float zzv = sZZ[px];
        int rawcnt = sKcnt[px];
        if (rawcnt == 1) {
            if (w == 0) sBestPack[px] = packvk(-1e30f, (int)sKbuf[px][0]);
        } else if (rawcnt <= KDEPTH) {
            for (int s = w; s < rawcnt; s += 4) {
                int k = (int)sKbuf[px][s];
                const float* ek = emb + k * EMB_DIM;
                float acc = 0.f;
                #pragma unroll 8
                for (int c = 0; c < EMB_DIM; ++c)   // sequential fmaf = BLAS order
                    acc = fmaf(ek[c], zl[c], acc);
                float v = (zzv + sE2[k]) - 2.0f * acc;  // exact np token sequence
                atomicMin(&sBestPack[px], packvk(v, k));
            }
        } else {                                   // overflow safety net (~never)
            for (int k = w; k < NUM_EMB; k += 4) {
                const float* ek = emb + k * EMB_DIM;
                float acc = 0.f;
                #pragma unroll 8
                for (int c = 0; c < EMB_DIM; ++c)
                    acc = fmaf(ek[c], zl[c], acc);
                float v = (zzv + sE2[k]) - 2.0f * acc;
                atomicMin(&sBestPack[px], packvk(v, k));
            }
        }
    }
    __syncthreads();

    // ===== enc + epilogue (z from LDS; coalesced z_q stores) =====
    if (tid < 64)
        enc_out[p0 + tid] = (float)(unsigned)(sBestPack[tid] & 0xFFFFFFFFull);
    {
        const int px = lane;
        int bestk = (int)(sBestPack[px] & 0xFFFFFFFFull);
        const float* eq = emb + bestk * EMB_DIM;
        const float* zl = &sZf[px * ZSTRIDE];
        float* op = zq_out + (size_t)b * (EMB_DIM * 4096) + hw0 + px;
        float ls = 0.f;
        #pragma unroll
        for (int j = 0; j < 16; ++j) {
            int c = 16 * w + j;
            float qv = eq[c];
            float d = qv - zl[c];
            ls = fmaf(d, d, ls);
            op[(size_t)c * 4096] = qv;
        }
        #pragma unroll
        for (int off = 32; off > 0; off >>= 1) ls += __shfl_down(ls, off, 64);
        if (lane == 0) atomicAdd(&wsAcc[blockIdx.x & (NACC - 1)], ls);
    }
}

__global__ void vq_final_ws(const float* __restrict__ wsAcc,
                            float* __restrict__ loss_out) {
    int lane = threadIdx.x;                       // 64 threads
    float v = wsAcc[lane];
    #pragma unroll
    for (int off = 32; off > 0; off >>= 1) v += __shfl_down(v, off, 64);
    if (lane == 0) loss_out[0] = v * (1.25f / (float)ZQ_ELEMS);
}

__global__ void vq_final_direct(float* __restrict__ loss_out) {
    loss_out[0] = loss_out[0] * (1.25f / (float)ZQ_ELEMS);
}

// ---------- fallback (round-6 passing kernel) if d_ws is too small ----------
__global__ __launch_bounds__(256) void vq_nn_fb(const float* __restrict__ z_e,
                                                const float* __restrict__ emb,
                                                float* __restrict__ zq_out,
                                                float* __restrict__ enc_out,
                                                float* __restrict__ loss_acc) {
    #pragma clang fp contract(off)
    __shared__ float s_e2[NUM_EMB];
    int tid = threadIdx.x;
    for (int k = tid; k < NUM_EMB; k += 256) s_e2[k] = np_sumsq64(emb + k * EMB_DIM);
    __syncthreads();
    int p = blockIdx.x * 256 + tid;
    int b = p >> 12, hw = p & 4095;
    const float* zp = z_e + (size_t)b * (EMB_DIM * 4096) + hw;
    float z[EMB_DIM];
    #pragma unroll
    for (int c = 0; c < EMB_DIM; ++c) z[c] = zp[(size_t)c * 4096];
    float zz = np_sumsq64(z);
    float b1 = 3.4e38f; int i1 = 0;
    #pragma unroll 2
    for (int k = 0; k < NUM_EMB; ++k) {
        const float* ek = emb + k * EMB_DIM;
        float acc = 0.f;
        #pragma unroll
        for (int c = 0; c < EMB_DIM; ++c) acc = fmaf(ek[c], z[c], acc);
        float sc = (zz + s_e2[k]) - 2.0f * acc;
        bool lt = sc < b1; b1 = lt ? sc : b1; i1 = lt ? k : i1;
    }
    const float* eq = emb + i1 * EMB_DIM;
    float* op = zq_out + (size_t)b * (EMB_DIM * 4096) + hw;
    float ls = 0.f;
    #pragma unroll
    for (int c = 0; c < EMB_DIM; ++c) {
        float q = eq[c]; float d = q - z[c];
        ls = fmaf(d, d, ls);
        op[(size_t)c * 4096] = q;
    }
    enc_out[p] = (float)i1;
    #pragma unroll
    for (int off = 32; off > 0; off >>= 1) ls += __shfl_down(ls, off, 64);
    if ((tid & 63) == 0) atomicAdd(loss_acc, ls);
}

extern "C" void kernel_launch(void* const* d_in, const int* in_sizes, int n_in,
                              void* d_out, int out_size, void* d_ws, size_t ws_size,
                              hipStream_t stream) {
    const float* z_e = (const float*)d_in[0];
    const float* emb = (const float*)d_in[1];
    float* out = (float*)d_out;
    float* loss_out = out + ZQ_ELEMS;
    float* enc_out  = out + ZQ_ELEMS + 1;

    if (ws_size >= 140 * 1024) {
        short* wsE   = (short*)d_ws;                       // 128 KB frag-order
        float* wsE2  = (float*)((char*)d_ws + 131072);     // 4 KB
        float* wsAcc = (float*)((char*)d_ws + 135168);     // 256 B
        vq_zero_ws<<<1, NACC, 0, stream>>>(loss_out, wsAcc);
        vq_prep<<<16, 256, 0, stream>>>(emb, wsE, wsE2);
        vq_mfma<<<NPIX / 64, 256, 0, stream>>>(z_e, emb, wsE, wsE2, out, enc_out, wsAcc);
        vq_final_ws<<<1, 64, 0, stream>>>(wsAcc, loss_out);
    } else {
        hipMemsetAsync(loss_out, 0, 4, stream);
        vq_nn_fb<<<NPIX / 256, 256, 0, stream>>>(z_e, emb, out, enc_out, loss_out);
        vq_final_direct<<<1, 1, 0, stream>>>(loss_out);
    }
}

// Round 15
// 92.449 us; speedup vs baseline: 11.3140x; 1.0314x over previous
//
#include <hip/hip_runtime.h>
#include <hip/hip_bf16.h>

#define NUM_EMB 1024
#define EMB_DIM 64
#define NPIX    131072                 // 32*64*64 pixels
#define ZQ_ELEMS 8388608               // NPIX * EMB_DIM
#define KDEPTH  16
#define ZSTRIDE 65                     // padded f32 LDS stride (conflict-free)
#define NACC    64                     // spread loss accumulators
#define BIAS    0.25f                  // makes screen scores positive (packable)

// d_out FLOAT32: [ z_q (8388608, b-c-h-w) | loss (1) | enc (131072) ]
// d_ws: [ E'frag 128KB | e2 f32 4KB | lossAcc f32[64] @135168 ]

typedef __attribute__((ext_vector_type(8))) short short8_t;  // bf16x8 frag
typedef __attribute__((ext_vector_type(4))) float f32x4;     // mfma acc

__device__ __forceinline__ unsigned umin32(unsigned a, unsigned b) { return a < b ? a : b; }
__device__ __forceinline__ unsigned umax32(unsigned a, unsigned b) { return a > b ? a : b; }

__global__ void vq_zero_ws(float* __restrict__ loss_out, float* __restrict__ wsAcc) {
    if (threadIdx.x == 0) loss_out[0] = 0.f;
    wsAcc[threadIdx.x] = 0.f;          // 64 threads
}

// numpy pairwise-sum (n=64, 8-accumulator) of x[j]^2 — token-identical to the
// round-5..14 PASSING kernels (bit-matches np.sum(x**2, axis=-1)).
__device__ __forceinline__ float np_sumsq64(const float* __restrict__ x) {
    float q[EMB_DIM];
    #pragma unroll
    for (int c = 0; c < EMB_DIM; ++c) q[c] = x[c] * x[c];
    float r0 = q[0], r1 = q[1], r2 = q[2], r3 = q[3];
    float r4 = q[4], r5 = q[5], r6 = q[6], r7 = q[7];
    #pragma unroll
    for (int g = 1; g < 8; ++g) {
        r0 += q[8 * g + 0]; r1 += q[8 * g + 1];
        r2 += q[8 * g + 2]; r3 += q[8 * g + 3];
        r4 += q[8 * g + 4]; r5 += q[8 * g + 5];
        r6 += q[8 * g + 6]; r7 += q[8 * g + 7];
    }
    return ((r0 + r1) + (r2 + r3)) + ((r4 + r5) + (r6 + r7));
}

__device__ __forceinline__ unsigned long long packvk(float v, int k) {
    unsigned u = __float_as_uint(v);
    u = (u & 0x80000000u) ? ~u : (u | 0x80000000u);   // monotonic f32 -> u32
    return ((unsigned long long)u << 32) | (unsigned)k;
}

// Prep: E'frag (swizzled for coalesced A-frag loads) + np-exact e2 (r10 form).
__global__ __launch_bounds__(256) void vq_prep(const float* __restrict__ emb,
                                               short* __restrict__ wsE,
                                               float* __restrict__ wsE2) {
    #pragma clang fp contract(off)
    int t    = blockIdx.x * 256 + threadIdx.x;    // grid = 16 x 256 = 4096
    int l    = t & 63;
    int ch   = (t >> 6) & 15;
    int q    = t >> 10;
    int code = q * 256 + ch * 16 + (l & 15);
    const float* ek = emb + code * EMB_DIM;
    #pragma unroll
    for (int h = 0; h < 2; ++h) {
        short8_t pk;
        #pragma unroll
        for (int j = 0; j < 8; ++j) {
            int chan = 32 * h + 8 * (l >> 4) + j;
            __hip_bfloat16 bv = __float2bfloat16(-2.0f * ek[chan]);
            unsigned short u; __builtin_memcpy(&u, &bv, 2);
            pk[j] = (short)u;
        }
        *(short8_t*)(wsE + t * 16 + h * 8) = pk;
    }
    if (t < NUM_EMB) wsE2[t] = np_sumsq64(emb + t * EMB_DIM);
}

// ---------------------------------------------------------------------------
// Main: r14 skeleton; screen reduction in PACKED u32 domain. Biased scores
// (C-init = e2+BIAS > 0) order as u32; pack index into low 10 mantissa bits
// (quantization <= 3.1e-5, covered by band guard +1e-4). Per value: 1
// v_and_or_b32 + 5 u32 min/max = top-3 with indices. Flag if p3 <= thr
// (lane may have dropped a 4th in-band) -> rare full recollect (r14 path).
// Eval: exact np-f32, 4 threads/pixel; rawcnt==1 certified shortcut.
// ---------------------------------------------------------------------------
__global__ __launch_bounds__(256, 4) void vq_mfma(const float* __restrict__ z_e,
                                                  const float* __restrict__ emb,
                                                  const short* __restrict__ wsE,
                                                  const float* __restrict__ wsE2,
                                                  float* __restrict__ zq_out,
                                                  float* __restrict__ enc_out,
                                                  float* __restrict__ wsAcc) {
    #pragma clang fp contract(off)
    __shared__ float sZf[64 * ZSTRIDE];           // 16.6 KB exact f32 z tile
    __shared__ float sE2[NUM_EMB];                // 4 KB (unbiased, for eval)
    __shared__ float sE2b[NUM_EMB];               // 4 KB (biased, for screen)
    __shared__ unsigned sMinP[4][64];             // 1 KB packed wave mins
    __shared__ float sBand[64];
    __shared__ float sThrF[64];
    __shared__ unsigned sThrP[64];
    __shared__ float sZZ[64];
    __shared__ unsigned long long sBestPack[64];  // (mono(v)<<32)|k
    __shared__ unsigned short sKbuf[64][KDEPTH];  // 2 KB
    __shared__ int   sKcnt[64];
    __shared__ int   sPxFlag[64];
    __shared__ int   sFlagAny;

    const int tid  = threadIdx.x;
    const int w    = tid >> 6;
    const int lane = tid & 63;
    const int p0   = blockIdx.x * 64;
    const int b    = p0 >> 12;                    // uniform (64 | 4096)
    const int hw0  = p0 & 4095;
    const float* base = z_e + (size_t)b * (EMB_DIM * 4096) + hw0;

    {
        f32x4 e2x = *(const f32x4*)&wsE2[tid * 4];
        *(f32x4*)&sE2[tid * 4] = e2x;
        f32x4 eb;
        eb[0] = e2x[0] + BIAS; eb[1] = e2x[1] + BIAS;
        eb[2] = e2x[2] + BIAS; eb[3] = e2x[3] + BIAS;
        *(f32x4*)&sE2b[tid * 4] = eb;
    }
    if (tid < 64) { sKcnt[tid] = 0; sBestPack[tid] = ~0ULL; sPxFlag[tid] = 0; }
    if (tid == 0) sFlagAny = 0;

    // --- tile load: thread -> pixel lane, channels 16w..16w+15 (coalesced) ---
    {
        const float* zp = base + lane;
        float v[16];
        #pragma unroll
        for (int j = 0; j < 16; ++j) v[j] = zp[(size_t)(16 * w + j) * 4096];
        #pragma unroll
        for (int j = 0; j < 16; ++j) sZf[lane * ZSTRIDE + 16 * w + j] = v[j];
    }
    __syncthreads();                               // B1

    // --- wave0: np-exact zz + band from LDS (overlaps other waves) ---
    if (w == 0) {
        const float* zl = &sZf[lane * ZSTRIDE];
        float rr[8] = {0,0,0,0,0,0,0,0};
        float sab = 0.f;
        #pragma unroll
        for (int g = 0; g < 8; ++g)
            #pragma unroll
            for (int j = 0; j < 8; ++j) {
                float zc = zl[8 * g + j];
                float qq = zc * zc;               // separate mul (contract off)
                rr[j] += qq;                      // g-ascending per j = np order
                sab += fabsf(zc);
            }
        sZZ[lane]   = ((rr[0] + rr[1]) + (rr[2] + rr[3])) + ((rr[4] + rr[5]) + (rr[6] + rr[7]));
        // band guard: +1e-4 covers packed 10-bit mantissa quantization (2x3.1e-5)
        sBand[lane] = 2.0f * (9e-6f * sab + 2e-5f) + 1e-4f;
    }

    // --- B fragments from f32 LDS, then PIN in VGPRs (no LDS remat) ---
    short8_t bfrag[4][2];
    #pragma unroll
    for (int pg = 0; pg < 4; ++pg)
        #pragma unroll
        for (int h = 0; h < 2; ++h) {
            int bpr = pg * 16 + (lane & 15);
            int c0  = 32 * h + 8 * (lane >> 4);
            short8_t pk;
            #pragma unroll
            for (int j = 0; j < 8; ++j) {
                __hip_bfloat16 bv = __float2bfloat16(sZf[bpr * ZSTRIDE + c0 + j]);
                unsigned short u; __builtin_memcpy(&u, &bv, 2);
                pk[j] = (short)u;
            }
            asm volatile("" : "+v"(pk));          // force materialization
            bfrag[pg][h] = pk;
        }

    const short8_t* ef = (const short8_t*)wsE + (size_t)w * 2048;

    // ===== SINGLE SCREEN PASS: packed u32 top-3 per (lane,pg) =====
    unsigned p1[4] = {~0u, ~0u, ~0u, ~0u};
    unsigned p2[4] = {~0u, ~0u, ~0u, ~0u};
    unsigned p3[4] = {~0u, ~0u, ~0u, ~0u};
    {
        short8_t A0 = ef[lane * 2 + 0];
        short8_t A1 = ef[lane * 2 + 1];
        #pragma unroll 1
        for (int ch = 0; ch < 16; ++ch) {
            int chn = ch < 15 ? ch + 1 : 15;
            short8_t N0 = ef[(chn * 64 + lane) * 2 + 0];
            short8_t N1 = ef[(chn * 64 + lane) * 2 + 1];
            int kbase = w * 256 + ch * 16 + 4 * (lane >> 4);
            f32x4 e2bv = *(const f32x4*)(&sE2b[kbase]);
            unsigned kb[4] = {(unsigned)kbase, (unsigned)kbase + 1u,
                              (unsigned)kbase + 2u, (unsigned)kbase + 3u};
            #pragma unroll
            for (int pg = 0; pg < 4; ++pg) {
                f32x4 acc = __builtin_amdgcn_mfma_f32_16x16x32_bf16(A0, bfrag[pg][0], e2bv, 0, 0, 0);
                acc = __builtin_amdgcn_mfma_f32_16x16x32_bf16(A1, bfrag[pg][1], acc, 0, 0, 0);
                #pragma unroll
                for (int j = 0; j < 4; ++j) {
                    unsigned t  = (__float_as_uint(acc[j]) & 0xFFFFFC00u) | kb[j];
                    unsigned n1 = umin32(p1[pg], t);
                    unsigned x1 = umax32(p1[pg], t);
                    unsigned n2 = umin32(p2[pg], x1);
                    unsigned x2 = umax32(p2[pg], x1);
                    unsigned n3 = umin32(p3[pg], x2);
                    p1[pg] = n1; p2[pg] = n2; p3[pg] = n3;
                }
            }
            A0 = N0; A1 = N1;
        }
    }

    // per-pixel global packed min across lane-groups, then waves
    #pragma unroll
    for (int pg = 0; pg < 4; ++pg) {
        unsigned g = p1[pg];
        g = umin32(g, (unsigned)__shfl_xor((int)g, 16, 64));
        g = umin32(g, (unsigned)__shfl_xor((int)g, 32, 64));
        if (lane < 16) sMinP[w][pg * 16 + lane] = g;
    }
    __syncthreads();                               // B2
    if (tid < 64) {
        unsigned gp = umin32(umin32(sMinP[0][tid], sMinP[1][tid]),
                             umin32(sMinP[2][tid], sMinP[3][tid]));
        float m    = __uint_as_float(gp & 0xFFFFFC00u);
        float thrF = m + sBand[tid];
        sThrF[tid] = thrF;
        sThrP[tid] = (__float_as_uint(thrF) & 0xFFFFFC00u) | 1023u;
    }
    __syncthreads();                               // B3

    // ===== EMIT: lane emits its top-3 packed entries <= thr; flag on p3 =====
    #pragma unroll
    for (int pg = 0; pg < 4; ++pg) {
        int px = pg * 16 + (lane & 15);
        unsigned thrp = sThrP[px];
        if (p1[pg] <= thrp) {
            int slot = atomicAdd(&sKcnt[px], 1);
            if (slot < KDEPTH) sKbuf[px][slot] = (unsigned short)(p1[pg] & 1023u);
        }
        if (p2[pg] <= thrp) {
            int slot = atomicAdd(&sKcnt[px], 1);
            if (slot < KDEPTH) sKbuf[px][slot] = (unsigned short)(p2[pg] & 1023u);
        }
        if (p3[pg] <= thrp) {                      // lane may have dropped a 4th
            int slot = atomicAdd(&sKcnt[px], 1);
            if (slot < KDEPTH) sKbuf[px][slot] = (unsigned short)(p3[pg] & 1023u);
            sPxFlag[px] = 1; sFlagAny = 1;
        }
    }
    __syncthreads();                               // B4

    // ===== RARE: flagged pixels -> full recollect (biased f32 compare) =====
    if (sFlagAny) {
        if (tid < 64 && sPxFlag[tid]) sKcnt[tid] = 0;
        __syncthreads();
        float thrB[4];
        #pragma unroll
        for (int pg = 0; pg < 4; ++pg) {
            int px = pg * 16 + (lane & 15);
            thrB[pg] = sPxFlag[px] ? sThrF[px] : -1e30f;
        }
        short8_t A0 = ef[lane * 2 + 0];
        short8_t A1 = ef[lane * 2 + 1];
        #pragma unroll 1
        for (int ch = 0; ch < 16; ++ch) {
            int chn = ch < 15 ? ch + 1 : 15;
            short8_t N0 = ef[(chn * 64 + lane) * 2 + 0];
            short8_t N1 = ef[(chn * 64 + lane) * 2 + 1];
            int kbase = w * 256 + ch * 16 + 4 * (lane >> 4);
            f32x4 e2bv = *(const f32x4*)(&sE2b[kbase]);
            #pragma unroll
            for (int pg = 0; pg < 4; ++pg) {
                f32x4 acc = __builtin_amdgcn_mfma_f32_16x16x32_bf16(A0, bfrag[pg][0], e2bv, 0, 0, 0);
                acc = __builtin_amdgcn_mfma_f32_16x16x32_bf16(A1, bfrag[pg][1], acc, 0, 0, 0);
                #pragma unroll
                for (int j = 0; j < 4; ++j) {
                    if (acc[j] <= thrB[pg]) {
                        int pix  = pg * 16 + (lane & 15);
                        int slot = atomicAdd(&sKcnt[pix], 1);
                        if (slot < KDEPTH) sKbuf[pix][slot] = (unsigned short)(kbase + j);
                    }
                }
            }
            A0 = N0; A1 = N1;
        }
        __syncthreads();
    }

    // ===== EXACT EVAL: 4 threads/pixel; rawcnt==1 certified shortcut =====
    {
        const int px = lane;
        const float* zl = &sZf[px * ZSTRIDE];
        float zzv = sZZ[px];
        int rawcnt = sKcnt[px];
        if (rawcnt == 1) {
            if (w == 0) sBestPack[px] = packvk(-1e30f, (int)sKbuf[px][0]);
        } else if (rawcnt <= KDEPTH) {
            for (int s = w; s < rawcnt; s += 4) {
                int k = (int)sKbuf[px][s];
                const float* ek = emb + k * EMB_DIM;
                float acc = 0.f;
                #pragma unroll 8
                for (int c = 0; c < EMB_DIM; ++c)   // sequential fmaf = BLAS order
                    acc = fmaf(ek[c], zl[c], acc);
                float v = (zzv + sE2[k]) - 2.0f * acc;  // exact np token sequence
                atomicMin(&sBestPack[px], packvk(v, k));
            }
        } else {                                   // overflow safety net (~never)
            for (int k = w; k < NUM_EMB; k += 4) {
                const float* ek = emb + k * EMB_DIM;
                float acc = 0.f;
                #pragma unroll 8
                for (int c = 0; c < EMB_DIM; ++c)
                    acc = fmaf(ek[c], zl[c], acc);
                float v = (zzv + sE2[k]) - 2.0f * acc;
                atomicMin(&sBestPack[px], packvk(v, k));
            }
        }
    }
    __syncthreads();

    // ===== enc + epilogue (z from LDS; coalesced z_q stores) =====
    if (tid < 64)
        enc_out[p0 + tid] = (float)(unsigned)(sBestPack[tid] & 0xFFFFFFFFull);
    {
        const int px = lane;
        int bestk = (int)(sBestPack[px] & 0xFFFFFFFFull);
        const float* eq = emb + bestk * EMB_DIM;
        const float* zl = &sZf[px * ZSTRIDE];
        float* op = zq_out + (size_t)b * (EMB_DIM * 4096) + hw0 + px;
        float ls = 0.f;
        #pragma unroll
        for (int j = 0; j < 16; ++j) {
            int c = 16 * w + j;
            float qv = eq[c];
            float d = qv - zl[c];
            ls = fmaf(d, d, ls);
            op[(size_t)c * 4096] = qv;
        }
        #pragma unroll
        for (int off = 32; off > 0; off >>= 1) ls += __shfl_down(ls, off, 64);
        if (lane == 0) atomicAdd(&wsAcc[blockIdx.x & (NACC - 1)], ls);
    }
}

__global__ void vq_final_ws(const float* __restrict__ wsAcc,
                            float* __restrict__ loss_out) {
    int lane = threadIdx.x;                       // 64 threads
    float v = wsAcc[lane];
    #pragma unroll
    for (int off = 32; off > 0; off >>= 1) v += __shfl_down(v, off, 64);
    if (lane == 0) loss_out[0] = v * (1.25f / (float)ZQ_ELEMS);
}

__global__ void vq_final_direct(float* __restrict__ loss_out) {
    loss_out[0] = loss_out[0] * (1.25f / (float)ZQ_ELEMS);
}

// ---------- fallback (round-6 passing kernel) if d_ws is too small ----------
__global__ __launch_bounds__(256) void vq_nn_fb(const float* __restrict__ z_e,
                                                const float* __restrict__ emb,
                                                float* __restrict__ zq_out,
                                                float* __restrict__ enc_out,
                                                float* __restrict__ loss_acc) {
    #pragma clang fp contract(off)
    __shared__ float s_e2[NUM_EMB];
    int tid = threadIdx.x;
    for (int k = tid; k < NUM_EMB; k += 256) s_e2[k] = np_sumsq64(emb + k * EMB_DIM);
    __syncthreads();
    int p = blockIdx.x * 256 + tid;
    int b = p >> 12, hw = p & 4095;
    const float* zp = z_e + (size_t)b * (EMB_DIM * 4096) + hw;
    float z[EMB_DIM];
    #pragma unroll
    for (int c = 0; c < EMB_DIM; ++c) z[c] = zp[(size_t)c * 4096];
    float zz = np_sumsq64(z);
    float b1 = 3.4e38f; int i1 = 0;
    #pragma unroll 2
    for (int k = 0; k < NUM_EMB; ++k) {
        const float* ek = emb + k * EMB_DIM;
        float acc = 0.f;
        #pragma unroll
        for (int c = 0; c < EMB_DIM; ++c) acc = fmaf(ek[c], z[c], acc);
        float sc = (zz + s_e2[k]) - 2.0f * acc;
        bool lt = sc < b1; b1 = lt ? sc : b1; i1 = lt ? k : i1;
    }
    const float* eq = emb + i1 * EMB_DIM;
    float* op = zq_out + (size_t)b * (EMB_DIM * 4096) + hw;
    float ls = 0.f;
    #pragma unroll
    for (int c = 0; c < EMB_DIM; ++c) {
        float q = eq[c]; float d = q - z[c];
        ls = fmaf(d, d, ls);
        op[(size_t)c * 4096] = q;
    }
    enc_out[p] = (float)i1;
    #pragma unroll
    for (int off = 32; off > 0; off >>= 1) ls += __shfl_down(ls, off, 64);
    if ((tid & 63) == 0) atomicAdd(loss_acc, ls);
}

extern "C" void kernel_launch(void* const* d_in, const int* in_sizes, int n_in,
                              void* d_out, int out_size, void* d_ws, size_t ws_size,
                              hipStream_t stream) {
    const float* z_e = (const float*)d_in[0];
    const float* emb = (const float*)d_in[1];
    float* out = (float*)d_out;
    float* loss_out = out + ZQ_ELEMS;
    float* enc_out  = out + ZQ_ELEMS + 1;

    if (ws_size >= 140 * 1024) {
        short* wsE   = (short*)d_ws;                       // 128 KB frag-order
        float* wsE2  = (float*)((char*)d_ws + 131072);     // 4 KB
        float* wsAcc = (float*)((char*)d_ws + 135168);     // 256 B
        vq_zero_ws<<<1, NACC, 0, stream>>>(loss_out, wsAcc);
        vq_prep<<<16, 256, 0, stream>>>(emb, wsE, wsE2);
        vq_mfma<<<NPIX / 64, 256, 0, stream>>>(z_e, emb, wsE, wsE2, out, enc_out, wsAcc);
        vq_final_ws<<<1, 64, 0, stream>>>(wsAcc, loss_out);
    } else {
        hipMemsetAsync(loss_out, 0, 4, stream);
        vq_nn_fb<<<NPIX / 256, 256, 0, stream>>>(z_e, emb, out, enc_out, loss_out);
        vq_final_direct<<<1, 1, 0, stream>>>(loss_out);
    }
}